// Round 6
// baseline (408.924 us; speedup 1.0000x reference)
//
#include <hip/hip_runtime.h>

// Problem: B=32, C=17, H=256, W=256 fp32.
// out = 0.5 * ( sum(m1?d:0)/sum(m1) + sum(m2?d:0)/(sum(m2)*C) )
//   m1 = target>0 per element; m2 = any(m1 over C) per (b,h,w); d = |input-target|.
//
// Session evidence:
//   R0-R2: depth 2..24 loads/thread, occ 8..19 waves/CU all = 2.77 TB/s with
//          4-KB extents -> not latency-bound; pattern-bound.
//   R3/R5: G=4 (16-KB extents, 512 blocks) + all-NT -> stage1 ~83 us, 3.4 TB/s.
//   R4:    selective NT (tgt L3-resident) -> SLOWER (95 us). Read rate is
//          capped regardless of source (HBM vs L3).
//   Harness fill (write-only, long contiguous runs) does 6.8 TB/s.
// R6 (this): extent-length probe. G=8 -> 32-KB contiguous extents, 256 blocks
//   (exactly 1/CU, 2 streams/CU, half the concurrent stream fronts of R5).
//   Single-variable change vs R5. If headline unchanged -> read plateau is
//   structural -> ROOFLINE.

#define QPB      16384                  // (H*W)/4 float4-quads per (b,c) plane
#define N_CH     17
#define N_BATCH  32
#define THREADS  256
#define G        8                      // quads per thread per channel
#define QUADS_PER_BLOCK (THREADS * G)   // 2048
#define BLK_PER_BATCH   (QPB / QUADS_PER_BLOCK)   // 8
#define N_BLOCKS (N_BATCH * BLK_PER_BATCH)        // 256

typedef float f32x4 __attribute__((ext_vector_type(4)));

struct Slot {
    float s1;
    float s2;
    unsigned int c1;
    unsigned int c2;
};

__device__ __forceinline__ f32x4 ntload(const f32x4* p) {
    return __builtin_nontemporal_load(p);
}

// Stage 1: each thread owns G=8 pixel-quad columns; channels looped c-major,
// quads g-minor, so each block sweeps one contiguous 32-KB extent per
// (array, channel) visit. All loads non-temporal (data touched once).
__global__ __launch_bounds__(256) void heatloss_stage1(
    const float* __restrict__ inp, const float* __restrict__ tgt,
    Slot* __restrict__ slots) {

    // XCD-contiguous remap (blocks round-robin XCDs; give each XCD one
    // contiguous q-range).
    const int blk = (blockIdx.x & 7) * (N_BLOCKS / 8) + (blockIdx.x >> 3);
    const int b  = blk >> 3;                               // / BLK_PER_BATCH
    const int rb = (blk & (BLK_PER_BATCH - 1)) * QUADS_PER_BLOCK;

    const size_t base = (size_t)b * (N_CH * QPB) + rb + threadIdx.x;
    const f32x4* __restrict__ tp = (const f32x4*)tgt + base;
    const f32x4* __restrict__ xp = (const f32x4*)inp + base;

    float s1 = 0.0f;
    unsigned int c1 = 0u;
    float sa[G][4];                 // per-pixel-column |d| sums across channels
    bool  an[G][4];                 // per-pixel-column any(t>0)
    #pragma unroll
    for (int g = 0; g < G; ++g)
        #pragma unroll
        for (int j = 0; j < 4; ++j) { sa[g][j] = 0.f; an[g][j] = false; }

    #pragma unroll
    for (int c = 0; c < N_CH; ++c) {
        #pragma unroll
        for (int g = 0; g < G; ++g) {
            const size_t off = (size_t)c * QPB + (size_t)g * THREADS;
            f32x4 t = ntload(tp + off);
            f32x4 x = ntload(xp + off);
            float d0 = fabsf(x.x - t.x);
            float d1 = fabsf(x.y - t.y);
            float d2 = fabsf(x.z - t.z);
            float d3 = fabsf(x.w - t.w);
            bool p0 = t.x > 0.f, p1 = t.y > 0.f, p2 = t.z > 0.f, p3 = t.w > 0.f;
            sa[g][0] += d0; sa[g][1] += d1; sa[g][2] += d2; sa[g][3] += d3;
            s1 += p0 ? d0 : 0.f;  c1 += p0 ? 1u : 0u;  an[g][0] = an[g][0] || p0;
            s1 += p1 ? d1 : 0.f;  c1 += p1 ? 1u : 0u;  an[g][1] = an[g][1] || p1;
            s1 += p2 ? d2 : 0.f;  c1 += p2 ? 1u : 0u;  an[g][2] = an[g][2] || p2;
            s1 += p3 ? d3 : 0.f;  c1 += p3 ? 1u : 0u;  an[g][3] = an[g][3] || p3;
        }
    }

    float s2 = 0.f;
    unsigned int c2 = 0u;
    #pragma unroll
    for (int g = 0; g < G; ++g) {
        #pragma unroll
        for (int j = 0; j < 4; ++j) {
            s2 += an[g][j] ? sa[g][j] : 0.f;
            c2 += an[g][j] ? 1u : 0u;
        }
    }

    // Intra-wave butterfly reduction (wave = 64 on gfx950)
    #pragma unroll
    for (int off = 32; off > 0; off >>= 1) {
        s1 += __shfl_down(s1, off);
        s2 += __shfl_down(s2, off);
        c1 += __shfl_down(c1, off);
        c2 += __shfl_down(c2, off);
    }

    __shared__ float ls1[4], ls2[4];
    __shared__ unsigned int lc1[4], lc2[4];
    const int wave = threadIdx.x >> 6;
    const int lane = threadIdx.x & 63;
    if (lane == 0) {
        ls1[wave] = s1; ls2[wave] = s2;
        lc1[wave] = c1; lc2[wave] = c2;
    }
    __syncthreads();
    if (threadIdx.x == 0) {
        Slot sl;
        sl.s1 = ls1[0] + ls1[1] + ls1[2] + ls1[3];
        sl.s2 = ls2[0] + ls2[1] + ls2[2] + ls2[3];
        sl.c1 = lc1[0] + lc1[1] + lc1[2] + lc1[3];
        sl.c2 = lc2[0] + lc2[1] + lc2[2] + lc2[3];
        slots[blockIdx.x] = sl;   // private slot — no contention
    }
}

// Stage 2: one block sums the 256 per-block slots (counts summed exactly as
// uints) and writes the final scalar.
__global__ __launch_bounds__(256) void heatloss_stage2(
    const Slot* __restrict__ slots, float* __restrict__ out) {

    float s1 = 0.f, s2 = 0.f;
    unsigned int c1 = 0u, c2 = 0u;
    for (int i = threadIdx.x; i < N_BLOCKS; i += 256) {
        Slot sl = slots[i];
        s1 += sl.s1; s2 += sl.s2; c1 += sl.c1; c2 += sl.c2;
    }
    #pragma unroll
    for (int off = 32; off > 0; off >>= 1) {
        s1 += __shfl_down(s1, off);
        s2 += __shfl_down(s2, off);
        c1 += __shfl_down(c1, off);
        c2 += __shfl_down(c2, off);
    }
    __shared__ float ls1[4], ls2[4];
    __shared__ unsigned int lc1[4], lc2[4];
    const int wave = threadIdx.x >> 6;
    const int lane = threadIdx.x & 63;
    if (lane == 0) {
        ls1[wave] = s1; ls2[wave] = s2;
        lc1[wave] = c1; lc2[wave] = c2;
    }
    __syncthreads();
    if (threadIdx.x == 0) {
        float S1 = ls1[0] + ls1[1] + ls1[2] + ls1[3];
        float S2 = ls2[0] + ls2[1] + ls2[2] + ls2[3];
        float C1 = (float)(lc1[0] + lc1[1] + lc1[2] + lc1[3]);
        float C2 = (float)(lc2[0] + lc2[1] + lc2[2] + lc2[3]);
        float mean1 = S1 / C1;
        float mean2 = S2 / (C2 * (float)N_CH);
        out[0] = 0.5f * (mean1 + mean2);
    }
}

extern "C" void kernel_launch(void* const* d_in, const int* in_sizes, int n_in,
                              void* d_out, int out_size, void* d_ws, size_t ws_size,
                              hipStream_t stream) {
    const float* inp = (const float*)d_in[0];
    const float* tgt = (const float*)d_in[1];
    // d_in[2] (masks) and d_in[3] (hull) are unused by the forward pass.
    float* out = (float*)d_out;
    Slot* slots = (Slot*)d_ws;   // 256 * 16 B = 4 KB scratch

    heatloss_stage1<<<N_BLOCKS, THREADS, 0, stream>>>(inp, tgt, slots);
    heatloss_stage2<<<1, 256, 0, stream>>>(slots, out);
}

// Round 7
// 322.770 us; speedup vs baseline: 1.2669x; 1.2669x over previous
//
#include <hip/hip_runtime.h>

// Problem: B=32, C=17, H=256, W=256 fp32.
// out = 0.5 * ( sum(m1?d:0)/sum(m1) + sum(m2?d:0)/(sum(m2)*C) )
//   m1 = target>0 per element; m2 = any(m1 over C) per (b,h,w); d = |input-target|.
//
// Session evidence:
//   R0-R2: depth/occupancy sweep, 4-KB extents -> 2.77 TB/s. Not latency-bound.
//   R3/R5: G=4, 16-KB extents, all-NT -> stage1 ~83 us, 3.4 TB/s (best).
//   R4:    selective NT (tgt L3-resident) -> 95 us. Read rate capped
//          regardless of source (HBM vs L3).
//   R6:    G=8 fully unrolled -> VGPR cap 256 + 2.3 KB/thread SCRATCH SPILL
//          (WRITE_SIZE 64 KB -> 154 MB) -> 144-184 us. VOID as an extent probe.
// R7 (this): G=8 retried cleanly: #pragma unroll 1 on the channel loop keeps
//   only one channel's 16 loads in flight (~150 VGPR, no spill). Depth 16 is
//   ample (R0-R2: depth >= 2 suffices). This is the clean 32-KB-extent probe.
//   Null result (~83 us) => read plateau structural => ROOFLINE on R5 config.

#define QPB      16384                  // (H*W)/4 float4-quads per (b,c) plane
#define N_CH     17
#define N_BATCH  32
#define THREADS  256
#define G        8                      // quads per thread per channel
#define QUADS_PER_BLOCK (THREADS * G)   // 2048
#define BLK_PER_BATCH   (QPB / QUADS_PER_BLOCK)   // 8
#define N_BLOCKS (N_BATCH * BLK_PER_BATCH)        // 256

typedef float f32x4 __attribute__((ext_vector_type(4)));

struct Slot {
    float s1;
    float s2;
    unsigned int c1;
    unsigned int c2;
};

__device__ __forceinline__ f32x4 ntload(const f32x4* p) {
    return __builtin_nontemporal_load(p);
}

// Stage 1: each thread owns G=8 pixel-quad columns; channels looped c-major
// (NOT unrolled — register control), quads g-minor (unrolled), so each block
// sweeps one contiguous 32-KB extent per (array, channel) visit. All loads
// non-temporal (data touched once per dispatch).
__global__ __launch_bounds__(256) void heatloss_stage1(
    const float* __restrict__ inp, const float* __restrict__ tgt,
    Slot* __restrict__ slots) {

    // XCD-contiguous remap (blocks round-robin XCDs; give each XCD one
    // contiguous q-range).
    const int blk = (blockIdx.x & 7) * (N_BLOCKS / 8) + (blockIdx.x >> 3);
    const int b  = blk >> 3;                               // / BLK_PER_BATCH
    const int rb = (blk & (BLK_PER_BATCH - 1)) * QUADS_PER_BLOCK;

    const size_t base = (size_t)b * (N_CH * QPB) + rb + threadIdx.x;
    const f32x4* __restrict__ tp = (const f32x4*)tgt + base;
    const f32x4* __restrict__ xp = (const f32x4*)inp + base;

    float s1 = 0.0f;
    unsigned int c1 = 0u;
    float sa[G][4];                 // per-pixel-column |d| sums across channels
    bool  an[G][4];                 // per-pixel-column any(t>0)
    #pragma unroll
    for (int g = 0; g < G; ++g)
        #pragma unroll
        for (int j = 0; j < 4; ++j) { sa[g][j] = 0.f; an[g][j] = false; }

    #pragma unroll 1                // register control: one channel in flight
    for (int c = 0; c < N_CH; ++c) {
        f32x4 t[G], x[G];
        // Issue all 16 loads of this channel back-to-back (depth 16 >> the
        // ~2 needed per R0-R2), then consume.
        #pragma unroll
        for (int g = 0; g < G; ++g) {
            const size_t off = (size_t)c * QPB + (size_t)g * THREADS;
            t[g] = ntload(tp + off);
            x[g] = ntload(xp + off);
        }
        #pragma unroll
        for (int g = 0; g < G; ++g) {
            float d0 = fabsf(x[g].x - t[g].x);
            float d1 = fabsf(x[g].y - t[g].y);
            float d2 = fabsf(x[g].z - t[g].z);
            float d3 = fabsf(x[g].w - t[g].w);
            bool p0 = t[g].x > 0.f, p1 = t[g].y > 0.f;
            bool p2 = t[g].z > 0.f, p3 = t[g].w > 0.f;
            sa[g][0] += d0; sa[g][1] += d1; sa[g][2] += d2; sa[g][3] += d3;
            s1 += p0 ? d0 : 0.f;  c1 += p0 ? 1u : 0u;  an[g][0] = an[g][0] || p0;
            s1 += p1 ? d1 : 0.f;  c1 += p1 ? 1u : 0u;  an[g][1] = an[g][1] || p1;
            s1 += p2 ? d2 : 0.f;  c1 += p2 ? 1u : 0u;  an[g][2] = an[g][2] || p2;
            s1 += p3 ? d3 : 0.f;  c1 += p3 ? 1u : 0u;  an[g][3] = an[g][3] || p3;
        }
    }

    float s2 = 0.f;
    unsigned int c2 = 0u;
    #pragma unroll
    for (int g = 0; g < G; ++g) {
        #pragma unroll
        for (int j = 0; j < 4; ++j) {
            s2 += an[g][j] ? sa[g][j] : 0.f;
            c2 += an[g][j] ? 1u : 0u;
        }
    }

    // Intra-wave butterfly reduction (wave = 64 on gfx950)
    #pragma unroll
    for (int off = 32; off > 0; off >>= 1) {
        s1 += __shfl_down(s1, off);
        s2 += __shfl_down(s2, off);
        c1 += __shfl_down(c1, off);
        c2 += __shfl_down(c2, off);
    }

    __shared__ float ls1[4], ls2[4];
    __shared__ unsigned int lc1[4], lc2[4];
    const int wave = threadIdx.x >> 6;
    const int lane = threadIdx.x & 63;
    if (lane == 0) {
        ls1[wave] = s1; ls2[wave] = s2;
        lc1[wave] = c1; lc2[wave] = c2;
    }
    __syncthreads();
    if (threadIdx.x == 0) {
        Slot sl;
        sl.s1 = ls1[0] + ls1[1] + ls1[2] + ls1[3];
        sl.s2 = ls2[0] + ls2[1] + ls2[2] + ls2[3];
        sl.c1 = lc1[0] + lc1[1] + lc1[2] + lc1[3];
        sl.c2 = lc2[0] + lc2[1] + lc2[2] + lc2[3];
        slots[blockIdx.x] = sl;   // private slot — no contention
    }
}

// Stage 2: one block sums the 256 per-block slots (counts summed exactly as
// uints) and writes the final scalar.
__global__ __launch_bounds__(256) void heatloss_stage2(
    const Slot* __restrict__ slots, float* __restrict__ out) {

    float s1 = 0.f, s2 = 0.f;
    unsigned int c1 = 0u, c2 = 0u;
    for (int i = threadIdx.x; i < N_BLOCKS; i += 256) {
        Slot sl = slots[i];
        s1 += sl.s1; s2 += sl.s2; c1 += sl.c1; c2 += sl.c2;
    }
    #pragma unroll
    for (int off = 32; off > 0; off >>= 1) {
        s1 += __shfl_down(s1, off);
        s2 += __shfl_down(s2, off);
        c1 += __shfl_down(c1, off);
        c2 += __shfl_down(c2, off);
    }
    __shared__ float ls1[4], ls2[4];
    __shared__ unsigned int lc1[4], lc2[4];
    const int wave = threadIdx.x >> 6;
    const int lane = threadIdx.x & 63;
    if (lane == 0) {
        ls1[wave] = s1; ls2[wave] = s2;
        lc1[wave] = c1; lc2[wave] = c2;
    }
    __syncthreads();
    if (threadIdx.x == 0) {
        float S1 = ls1[0] + ls1[1] + ls1[2] + ls1[3];
        float S2 = ls2[0] + ls2[1] + ls2[2] + ls2[3];
        float C1 = (float)(lc1[0] + lc1[1] + lc1[2] + lc1[3]);
        float C2 = (float)(lc2[0] + lc2[1] + lc2[2] + lc2[3]);
        float mean1 = S1 / C1;
        float mean2 = S2 / (C2 * (float)N_CH);
        out[0] = 0.5f * (mean1 + mean2);
    }
}

extern "C" void kernel_launch(void* const* d_in, const int* in_sizes, int n_in,
                              void* d_out, int out_size, void* d_ws, size_t ws_size,
                              hipStream_t stream) {
    const float* inp = (const float*)d_in[0];
    const float* tgt = (const float*)d_in[1];
    // d_in[2] (masks) and d_in[3] (hull) are unused by the forward pass.
    float* out = (float*)d_out;
    Slot* slots = (Slot*)d_ws;   // 256 * 16 B = 4 KB scratch

    heatloss_stage1<<<N_BLOCKS, THREADS, 0, stream>>>(inp, tgt, slots);
    heatloss_stage2<<<1, 256, 0, stream>>>(slots, out);
}